// Round 5
// baseline (1105.860 us; speedup 1.0000x reference)
//
#include <hip/hip_runtime.h>
#include <cstdint>
#include <cstddef>

typedef _Float16 h8 __attribute__((ext_vector_type(8)));
typedef float f4 __attribute__((ext_vector_type(4)));
typedef float f16f __attribute__((ext_vector_type(16)));

#define DEV static __device__ __forceinline__

DEV void gld16(const void* g, void* l) {
  __builtin_amdgcn_global_load_lds(
      (const __attribute__((address_space(1))) void*)g,
      (__attribute__((address_space(3))) void*)l, 16, 0, 0);
}

// ---------- FastKAN prep: LayerNorm + RBF basis + SiLU -> Acat [M][6912] fp16
__global__ __launch_bounds__(256)
void kan_prep(const float* __restrict__ X, const float* __restrict__ lnw,
              const float* __restrict__ lnb, _Float16* __restrict__ Acat) {
  const int row = blockIdx.x;
  const int tid = threadIdx.x;
  const float* xr = X + (size_t)row * 768;
  float xv[3];
  xv[0] = xr[tid]; xv[1] = xr[tid + 256]; xv[2] = xr[tid + 512];
  float s = xv[0] + xv[1] + xv[2];
  float q = xv[0] * xv[0] + xv[1] * xv[1] + xv[2] * xv[2];
#pragma unroll
  for (int off = 32; off; off >>= 1) {
    s += __shfl_xor(s, off);
    q += __shfl_xor(q, off);
  }
  __shared__ float rs_[4], rq_[4];
  const int wave = tid >> 6;
  if ((tid & 63) == 0) { rs_[wave] = s; rq_[wave] = q; }
  __syncthreads();
  s = rs_[0] + rs_[1] + rs_[2] + rs_[3];
  q = rq_[0] + rq_[1] + rq_[2] + rq_[3];
  const float mu = s * (1.0f / 768.0f);
  const float var = q * (1.0f / 768.0f) - mu * mu;
  const float rsig = rsqrtf(var + 1e-5f);
  _Float16* out = Acat + (size_t)row * 6912;
#pragma unroll
  for (int i = 0; i < 3; ++i) {
    const int c = tid + i * 256;
    const float x = xv[i];
    const float h = (x - mu) * rsig * lnw[c] + lnb[c];
    union { h8 v; _Float16 u[8]; } bs;
#pragma unroll
    for (int g = 0; g < 8; ++g) {
      const float gv = -2.0f + (4.0f / 7.0f) * (float)g;
      const float t = (h - gv) * 1.75f;  // 1/DENOM = 7/4
      bs.u[g] = (_Float16)__expf(-t * t);
    }
    *(h8*)(out + c * 8) = bs.v;
    out[6144 + c] = (_Float16)(x / (1.0f + __expf(-x)));  // silu
  }
}

// ---------- weight cast+transpose: W fp32 [K][N] -> Wt fp16 [N][6912] at col koff
__global__ __launch_bounds__(256)
void wt_cast(const float* __restrict__ W, _Float16* __restrict__ Wt,
             int N, int koff) {
  __shared__ float t[32][33];
  const int k0 = blockIdx.x * 32, n0 = blockIdx.y * 32;
  const int tx = threadIdx.x & 31, ty = threadIdx.x >> 5;
#pragma unroll
  for (int i = 0; i < 4; ++i)
    t[ty + i * 8][tx] = W[(size_t)(k0 + ty + i * 8) * N + n0 + tx];
  __syncthreads();
#pragma unroll
  for (int i = 0; i < 4; ++i) {
    const int n = n0 + ty + i * 8;
    Wt[(size_t)n * 6912 + koff + k0 + tx] = (_Float16)t[tx][ty + i * 8];
  }
}

// ---------- V transpose: qkv fp16 [8192][2304] -> Vt [96*64][1024]
__global__ __launch_bounds__(256)
void v_transpose(const _Float16* __restrict__ qkv, _Float16* __restrict__ Vt) {
  const int bh = blockIdx.z, hh = bh % 12, b = bh / 12;
  const int kvb = blockIdx.x * 32, db = blockIdx.y * 32;
  __shared__ _Float16 t[32][33];
  const int tx = threadIdx.x & 31, ty = threadIdx.x >> 5;
#pragma unroll
  for (int i = 0; i < 4; ++i) {
    const int kv = kvb + ty + i * 8;
    t[ty + i * 8][tx] = qkv[(size_t)(b * 1024 + kv) * 2304 + 1536 + hh * 64 + db + tx];
  }
  __syncthreads();
#pragma unroll
  for (int i = 0; i < 4; ++i) {
    const int d = db + ty + i * 8;
    Vt[(size_t)(bh * 64 + d) * 1024 + kvb + tx] = t[tx][ty + i * 8];
  }
}

// ---------- fp16 GEMM (32x32x16 MFMA): C = A[M][ldK-slice] * Bt[N][..]^T
// 128x128 tile, BK=64, 4 waves (2x2 of 64x64, each 2x2 of 32x32 MFMA tiles).
// r5: A staged via global_load_lds (LDS 16KB, swizzled); B read DIRECT from
// global (L2-resident weights) into VGPRs in natural (2ks+half) chunk order —
// halves LDS read traffic (the r4 measured bottleneck: ~1615 cyc/block-iter
// vs 771-cyc LDS floor at 85 B/cyc). B loads drain on the same vmcnt(0)
// barrier the A-DMA already pays for.
template <bool F16OUT>
__global__ __launch_bounds__(256, 3)
void gemm_bt(const _Float16* __restrict__ A, const _Float16* __restrict__ Bt,
             const float* __restrict__ bias, void* __restrict__ Cout,
             int N, int ldK, int kLen, size_t sliceStride) {
  __shared__ __align__(16) _Float16 As[128 * 64];
  const int tid = threadIdx.x;
  const int lane = tid & 63, wave = tid >> 6;
  const int bm = blockIdx.y * 128, bn = blockIdx.x * 128;
  const int slice = blockIdx.z;
  const int kOff = slice * kLen;
  const int rsub = lane >> 3;                 // row within 8-row staging chunk
  const int l7 = lane & 7;
  const int l31 = lane & 31, half = lane >> 5;
  const int wm = (wave >> 1) * 64, wn = (wave & 1) * 64;
  const _Float16* ap[4];
  _Float16* al[4];
#pragma unroll
  for (int i = 0; i < 4; ++i) {
    const int ch = wave * 4 + i;
    // lane -> global chunk permutation implementing the swizzled store:
    // chunk c of row r lands at slot r*8 + (c ^ (r&7) ^ ((r>>3&3)<<1))
    const int ksw = (l7 ^ rsub ^ ((ch & 3) << 1)) * 8;
    ap[i] = A + (size_t)(bm + ch * 8 + rsub) * ldK + kOff + ksw;
    al[i] = As + ch * 512;
  }
  // B direct-load base: row = bn + wn + ni*32 + l31, chunk parity from half
  const _Float16* bp2[2];
#pragma unroll
  for (int ni = 0; ni < 2; ++ni)
    bp2[ni] = Bt + (size_t)(bn + wn + ni * 32 + l31) * ldK + kOff + half * 8;

  f16f acc[2][2] = {};
  const int swz = l7 ^ ((rsub & 3) << 1);     // row-dependent part of read swizzle
  const int nkt = kLen >> 6;
  for (int kt = 0; kt < nkt; ++kt) {
    // B fragments: global -> VGPR, natural chunk order (2ks+half)
    h8 breg[2][4];
#pragma unroll
    for (int ni = 0; ni < 2; ++ni)
#pragma unroll
      for (int ks = 0; ks < 4; ++ks)
        breg[ni][ks] = *(const h8*)(bp2[ni] + ks * 16);
    // A tile: global -> LDS DMA
#pragma unroll
    for (int i = 0; i < 4; ++i) {
      gld16(ap[i], al[i]);
      ap[i] += 64;
    }
#pragma unroll
    for (int ni = 0; ni < 2; ++ni) bp2[ni] += 64;
    __syncthreads();   // drains vmcnt(0): both A-DMA and B loads complete
    const h8* A8 = (const h8*)As;
#pragma unroll
    for (int ks = 0; ks < 4; ++ks) {
      const int o = (ks * 2 + half) ^ swz;  // swizzled 16B-chunk index
      h8 af[2];
#pragma unroll
      for (int mi = 0; mi < 2; ++mi) af[mi] = A8[(wm + mi * 32 + l31) * 8 + o];
#pragma unroll
      for (int mi = 0; mi < 2; ++mi)
#pragma unroll
        for (int ni = 0; ni < 2; ++ni)
          acc[mi][ni] = __builtin_amdgcn_mfma_f32_32x32x16_f16(af[mi], breg[ni][ks], acc[mi][ni], 0, 0, 0);
    }
    __syncthreads();
  }
  // epilogue: 32x32 C/D layout col=lane&31, row=(reg&3)+8*(reg>>2)+4*(lane>>5)
#pragma unroll
  for (int ni = 0; ni < 2; ++ni) {
    const int col = bn + wn + ni * 32 + l31;
    const float bv = F16OUT ? bias[col] : 0.0f;
#pragma unroll
    for (int mi = 0; mi < 2; ++mi) {
      const int rb = bm + wm + mi * 32 + 4 * half;
#pragma unroll
      for (int reg = 0; reg < 16; ++reg) {
        const int r = rb + (reg & 3) + 8 * (reg >> 2);
        const float v = acc[mi][ni][reg] + bv;
        if (F16OUT)
          ((_Float16*)Cout)[(size_t)r * N + col] = (_Float16)v;
        else
          ((float*)Cout + slice * sliceStride)[(size_t)r * N + col] = v;
      }
    }
  }
}

// ---------- split-K reduce: out = P0 + P1 + bias  (fp32, [8192][768])
__global__ __launch_bounds__(256)
void ksum2(const float* __restrict__ P, const float* __restrict__ bias,
           float* __restrict__ out) {
  const size_t off = ((size_t)blockIdx.x * 256 + threadIdx.x) * 4;
  const int col = (int)(off % 768);
  f4 a = *(const f4*)(P + off);
  f4 b = *(const f4*)(P + (size_t)8192 * 768 + off);
  f4 c = *(const f4*)(bias + col);
  *(f4*)(out + off) = a + b + c;
}

// ---------- flash attention: grid (8 q-tiles, 96 bh). Q-tile 128, KV-tile 64.
__global__ __launch_bounds__(256)
void attn(const _Float16* __restrict__ qkv, const _Float16* __restrict__ Vt,
          float* __restrict__ ctx) {
  __shared__ __align__(16) _Float16 Qs[128 * 64];
  __shared__ __align__(16) _Float16 Ks[64 * 64];
  __shared__ __align__(16) _Float16 Vs[64 * 64];
  __shared__ __align__(16) _Float16 Ps[4 * 32 * 72];
  const int tid = threadIdx.x;
  const int lane = tid & 63, wave = tid >> 6;
  const int bh = blockIdx.y, hh = bh % 12, b = bh / 12;
  const int qt = blockIdx.x;
  const int rsub = lane >> 3;
  const int ksw = ((lane & 7) ^ rsub) * 8;
#pragma unroll
  for (int i = 0; i < 4; ++i) {
    const int ch = wave * 4 + i;
    const int row = ch * 8 + rsub;
    gld16(qkv + (size_t)(b * 1024 + qt * 128 + row) * 2304 + hh * 64 + ksw, Qs + ch * 512);
  }
  const int l16 = lane & 15, quad = lane >> 4, r7 = l16 & 7;
  f4 acc_o[2][4] = {};
  float m_old[2][4], l_sum[2][4];
#pragma unroll
  for (int mi = 0; mi < 2; ++mi)
#pragma unroll
    for (int j = 0; j < 4; ++j) { m_old[mi][j] = -1e30f; l_sum[mi][j] = 0.0f; }

  _Float16* Pw = Ps + wave * (32 * 72);

  for (int kv0 = 0; kv0 < 1024; kv0 += 64) {
#pragma unroll
    for (int i = 0; i < 2; ++i) {
      const int ch = wave * 2 + i;
      const int row = ch * 8 + rsub;
      gld16(qkv + (size_t)(b * 1024 + kv0 + row) * 2304 + 768 + hh * 64 + ksw, Ks + ch * 512);
      gld16(Vt + (size_t)(bh * 64 + row) * 1024 + kv0 + ksw, Vs + ch * 512);
    }
    __syncthreads();
    const h8* Q8 = (const h8*)Qs;
    const h8* K8 = (const h8*)Ks;
    const h8* V8 = (const h8*)Vs;
    f4 s[2][4] = {};
#pragma unroll
    for (int ks = 0; ks < 2; ++ks) {
      const int kq = (ks * 4 + quad) ^ r7;
      h8 qf[2], kf[4];
#pragma unroll
      for (int mi = 0; mi < 2; ++mi) qf[mi] = Q8[(wave * 32 + mi * 16 + l16) * 8 + kq];
#pragma unroll
      for (int ni = 0; ni < 4; ++ni) kf[ni] = K8[(ni * 16 + l16) * 8 + kq];
#pragma unroll
      for (int mi = 0; mi < 2; ++mi)
#pragma unroll
        for (int ni = 0; ni < 4; ++ni)
          s[mi][ni] = __builtin_amdgcn_mfma_f32_16x16x32_f16(qf[mi], kf[ni], s[mi][ni], 0, 0, 0);
    }
#pragma unroll
    for (int mi = 0; mi < 2; ++mi)
#pragma unroll
      for (int ni = 0; ni < 4; ++ni) s[mi][ni] *= 0.125f;  // d^-0.5, d=64
#pragma unroll
    for (int mi = 0; mi < 2; ++mi) {
#pragma unroll
      for (int j = 0; j < 4; ++j) {
        float vm = fmaxf(fmaxf(s[mi][0][j], s[mi][1][j]), fmaxf(s[mi][2][j], s[mi][3][j]));
#pragma unroll
        for (int off = 1; off < 16; off <<= 1) vm = fmaxf(vm, __shfl_xor(vm, off));
        const float mn = fmaxf(m_old[mi][j], vm);
        const float alpha = __expf(m_old[mi][j] - mn);
        float rs = 0.0f;
#pragma unroll
        for (int ni = 0; ni < 4; ++ni) {
          const float p = __expf(s[mi][ni][j] - mn);
          s[mi][ni][j] = p;
          rs += p;
        }
#pragma unroll
        for (int off = 1; off < 16; off <<= 1) rs += __shfl_xor(rs, off);
        l_sum[mi][j] = l_sum[mi][j] * alpha + rs;
        m_old[mi][j] = mn;
#pragma unroll
        for (int ni = 0; ni < 4; ++ni) acc_o[mi][ni][j] *= alpha;
      }
    }
#pragma unroll
    for (int mi = 0; mi < 2; ++mi)
#pragma unroll
      for (int ni = 0; ni < 4; ++ni)
#pragma unroll
        for (int j = 0; j < 4; ++j)
          Pw[(mi * 16 + quad * 4 + j) * 72 + ni * 16 + l16] = (_Float16)s[mi][ni][j];
#pragma unroll
    for (int ks = 0; ks < 2; ++ks) {
      const int kq = ks * 4 + quad;
      h8 pf[2], vf[4];
#pragma unroll
      for (int mi = 0; mi < 2; ++mi) pf[mi] = *(const h8*)(Pw + (mi * 16 + l16) * 72 + kq * 8);
#pragma unroll
      for (int ni = 0; ni < 4; ++ni) vf[ni] = V8[(ni * 16 + l16) * 8 + (kq ^ r7)];
#pragma unroll
      for (int mi = 0; mi < 2; ++mi)
#pragma unroll
        for (int ni = 0; ni < 4; ++ni)
          acc_o[mi][ni] = __builtin_amdgcn_mfma_f32_16x16x32_f16(pf[mi], vf[ni], acc_o[mi][ni], 0, 0, 0);
    }
    __syncthreads();
  }
#pragma unroll
  for (int mi = 0; mi < 2; ++mi) {
#pragma unroll
    for (int j = 0; j < 4; ++j) {
      const float inv = 1.0f / l_sum[mi][j];
      const int tok = b * 1024 + qt * 128 + wave * 32 + mi * 16 + quad * 4 + j;
      float* cr = ctx + (size_t)tok * 768 + hh * 64;
#pragma unroll
      for (int ni = 0; ni < 4; ++ni) cr[ni * 16 + l16] = acc_o[mi][ni][j] * inv;
    }
  }
}

extern "C" void kernel_launch(void* const* d_in, const int* in_sizes, int n_in,
                              void* d_out, int out_size, void* d_ws, size_t ws_size,
                              hipStream_t stream) {
  (void)in_sizes; (void)n_in; (void)out_size; (void)ws_size;
  const float* x    = (const float*)d_in[0];
  const float* qlnw = (const float*)d_in[1];
  const float* qlnb = (const float*)d_in[2];
  const float* qsw  = (const float*)d_in[3];
  const float* qbw  = (const float*)d_in[4];
  const float* qbb  = (const float*)d_in[5];
  const float* plnw = (const float*)d_in[6];
  const float* plnb = (const float*)d_in[7];
  const float* psw  = (const float*)d_in[8];
  const float* pbw  = (const float*)d_in[9];
  const float* pbb  = (const float*)d_in[10];
  float* out = (float*)d_out;

  // workspace layout (fp16 unless noted), ~231 MB total
  _Float16* WtQ  = (_Float16*)d_ws;                  // [2304][6912]
  _Float16* WtP  = WtQ + (size_t)2304 * 6912;        // [768][6912]
  _Float16* Acat = WtP + (size_t)768 * 6912;         // [8192][6912] (reused)
  _Float16* QKV  = Acat + (size_t)8192 * 6912;       // [8192][2304]
  _Float16* Vt   = QKV + (size_t)8192 * 2304;        // [96*64][1024]
  float* CTX = (float*)(Vt + (size_t)96 * 64 * 1024);  // [8192][768] fp32
  // split-K partials alias the dead QKV+Vt region (exactly 2*8192*768*4 B)
  float* Pp = (float*)QKV;

  dim3 blk(256);
  // weights -> fp16, transposed+concatenated [N][6912]
  wt_cast<<<dim3(192, 72), blk, 0, stream>>>(qsw, WtQ, 2304, 0);
  wt_cast<<<dim3(24, 72),  blk, 0, stream>>>(qbw, WtQ, 2304, 6144);
  wt_cast<<<dim3(192, 24), blk, 0, stream>>>(psw, WtP, 768, 0);
  wt_cast<<<dim3(24, 24),  blk, 0, stream>>>(pbw, WtP, 768, 6144);
  // FastKAN 1 -> qkv
  kan_prep<<<8192, blk, 0, stream>>>(x, qlnw, qlnb, Acat);
  gemm_bt<true><<<dim3(2304 / 128, 8192 / 128, 1), blk, 0, stream>>>(
      Acat, WtQ, qbb, QKV, 2304, 6912, 6912, 0);
  // attention
  v_transpose<<<dim3(32, 2, 96), blk, 0, stream>>>(QKV, Vt);
  attn<<<dim3(8, 96), blk, 0, stream>>>(QKV, Vt, CTX);
  // FastKAN 2 -> out (split-K=2 over dead QKV/Vt memory, then reduce+bias)
  kan_prep<<<8192, blk, 0, stream>>>(CTX, plnw, plnb, Acat);
  gemm_bt<false><<<dim3(768 / 128, 8192 / 128, 2), blk, 0, stream>>>(
      Acat, WtP, nullptr, Pp, 768, 6912, 3456, (size_t)8192 * 768);
  ksum2<<<8192 * 768 / 4 / 256, blk, 0, stream>>>(Pp, pbb, out);
}

// Round 6
// 762.606 us; speedup vs baseline: 1.4501x; 1.4501x over previous
//
#include <hip/hip_runtime.h>
#include <cstdint>
#include <cstddef>

typedef _Float16 h8 __attribute__((ext_vector_type(8)));
typedef float f4 __attribute__((ext_vector_type(4)));
typedef float f16f __attribute__((ext_vector_type(16)));

#define DEV static __device__ __forceinline__

DEV void gld16(const void* g, void* l) {
  __builtin_amdgcn_global_load_lds(
      (const __attribute__((address_space(1))) void*)g,
      (__attribute__((address_space(3))) void*)l, 16, 0, 0);
}

// ---------- FastKAN prep: LayerNorm + RBF basis + SiLU -> Acat [M][6912] fp16
__global__ __launch_bounds__(256)
void kan_prep(const float* __restrict__ X, const float* __restrict__ lnw,
              const float* __restrict__ lnb, _Float16* __restrict__ Acat) {
  const int row = blockIdx.x;
  const int tid = threadIdx.x;
  const float* xr = X + (size_t)row * 768;
  float xv[3];
  xv[0] = xr[tid]; xv[1] = xr[tid + 256]; xv[2] = xr[tid + 512];
  float s = xv[0] + xv[1] + xv[2];
  float q = xv[0] * xv[0] + xv[1] * xv[1] + xv[2] * xv[2];
#pragma unroll
  for (int off = 32; off; off >>= 1) {
    s += __shfl_xor(s, off);
    q += __shfl_xor(q, off);
  }
  __shared__ float rs_[4], rq_[4];
  const int wave = tid >> 6;
  if ((tid & 63) == 0) { rs_[wave] = s; rq_[wave] = q; }
  __syncthreads();
  s = rs_[0] + rs_[1] + rs_[2] + rs_[3];
  q = rq_[0] + rq_[1] + rq_[2] + rq_[3];
  const float mu = s * (1.0f / 768.0f);
  const float var = q * (1.0f / 768.0f) - mu * mu;
  const float rsig = rsqrtf(var + 1e-5f);
  _Float16* out = Acat + (size_t)row * 6912;
#pragma unroll
  for (int i = 0; i < 3; ++i) {
    const int c = tid + i * 256;
    const float x = xv[i];
    const float h = (x - mu) * rsig * lnw[c] + lnb[c];
    union { h8 v; _Float16 u[8]; } bs;
#pragma unroll
    for (int g = 0; g < 8; ++g) {
      const float gv = -2.0f + (4.0f / 7.0f) * (float)g;
      const float t = (h - gv) * 1.75f;  // 1/DENOM = 7/4
      bs.u[g] = (_Float16)__expf(-t * t);
    }
    *(h8*)(out + c * 8) = bs.v;
    out[6144 + c] = (_Float16)(x / (1.0f + __expf(-x)));  // silu
  }
}

// ---------- weight cast + FRAGMENT-SWIZZLE: W fp32 [K][N] -> Bp fp16 in exact
// MFMA B-fragment order: 16B frag (n, k..k+7) at elem addr
//   ((n>>5)*nkt + (k>>6))*2048 + (((k>>4)&3)*64 + (n&31) + 32*((k>>3)&1))*8
// so GEMM lane l reads its fragment at base + l*8 -> coalesced 1KB loads.
__global__ __launch_bounds__(256)
void wt_cast(const float* __restrict__ W, _Float16* __restrict__ Bp,
             int N, int koff, int nkt) {
  __shared__ float t[32][33];
  const int k0 = blockIdx.x * 32, n0 = blockIdx.y * 32;
  const int tx = threadIdx.x & 31, ty = threadIdx.x >> 5;
#pragma unroll
  for (int i = 0; i < 4; ++i)
    t[ty + i * 8][tx] = W[(size_t)(k0 + ty + i * 8) * N + n0 + tx];
  __syncthreads();
  const int f = threadIdx.x;
  if (f < 128) {
    const int nn = f & 31, cc = f >> 5;          // cc: which 8-elem k-chunk
    union { h8 v; _Float16 u[8]; } bs;
#pragma unroll
    for (int j = 0; j < 8; ++j) bs.u[j] = (_Float16)t[cc * 8 + j][nn];
    const int kg = koff + k0 + cc * 8;           // global k of chunk start
    const int nt = (n0 + nn) >> 5;
    const size_t addr = ((size_t)nt * nkt + (kg >> 6)) * 2048 +
                        (size_t)((((kg >> 4) & 3) * 64 + nn + 32 * ((kg >> 3) & 1))) * 8;
    *(h8*)(Bp + addr) = bs.v;
  }
}

// ---------- V transpose: qkv fp16 [8192][2304] -> Vt [96*64][1024]
__global__ __launch_bounds__(256)
void v_transpose(const _Float16* __restrict__ qkv, _Float16* __restrict__ Vt) {
  const int bh = blockIdx.z, hh = bh % 12, b = bh / 12;
  const int kvb = blockIdx.x * 32, db = blockIdx.y * 32;
  __shared__ _Float16 t[32][33];
  const int tx = threadIdx.x & 31, ty = threadIdx.x >> 5;
#pragma unroll
  for (int i = 0; i < 4; ++i) {
    const int kv = kvb + ty + i * 8;
    t[ty + i * 8][tx] = qkv[(size_t)(b * 1024 + kv) * 2304 + 1536 + hh * 64 + db + tx];
  }
  __syncthreads();
#pragma unroll
  for (int i = 0; i < 4; ++i) {
    const int d = db + ty + i * 8;
    Vt[(size_t)(bh * 64 + d) * 1024 + kvb + tx] = t[tx][ty + i * 8];
  }
}

// ---------- fp16 GEMM (32x32x16 MFMA): C = A[M][K] * B'^T + bias
// 128x128 tile, BK=64, 4 waves (2x2 of 64x64). A staged via global_load_lds
// (16KB, swizzled); B read from pre-swizzled fragment-order global (coalesced
// 1KB dwordx4, L3-resident, no LDS). Per-block-iter LDS traffic 48KB (~500cyc)
// vs MFMA 512cyc -> MFMA-bound (r5 lesson: B-by-row was uncoalesced; r4
// lesson: SQ_LDS_BANK_CONFLICT tracks DMA LDS-writes, not ds_read).
template <bool F16OUT>
__global__ __launch_bounds__(256, 3)
void gemm_bt(const _Float16* __restrict__ A, const _Float16* __restrict__ Bp,
             const float* __restrict__ bias, void* __restrict__ Cout,
             int N, int ldK, int kLen, size_t sliceStride) {
  __shared__ __align__(16) _Float16 As[128 * 64];
  const int tid = threadIdx.x;
  const int lane = tid & 63, wave = tid >> 6;
  const int bm = blockIdx.y * 128, bn = blockIdx.x * 128;
  const int slice = blockIdx.z;
  const int kOff = slice * kLen;
  const int rsub = lane >> 3;                 // row within 8-row staging chunk
  const int l7 = lane & 7;
  const int l31 = lane & 31, half = lane >> 5;
  const int wm = (wave >> 1) * 64, wn = (wave & 1) * 64;
  const _Float16* ap[4];
  _Float16* al[4];
#pragma unroll
  for (int i = 0; i < 4; ++i) {
    const int ch = wave * 4 + i;
    // lane -> global chunk permutation implementing the swizzled store:
    // chunk c of row r lands at slot r*8 + (c ^ (r&7) ^ ((r>>3&3)<<1))
    const int ksw = (l7 ^ rsub ^ ((ch & 3) << 1)) * 8;
    ap[i] = A + (size_t)(bm + ch * 8 + rsub) * ldK + kOff + ksw;
    al[i] = As + ch * 512;
  }
  // B fragment-order bases: nt = (bn + wn + ni*32)>>5
  const size_t nktTot = (size_t)(ldK >> 6);
  const int kt0 = kOff >> 6;
  const _Float16* bpp[2];
#pragma unroll
  for (int ni = 0; ni < 2; ++ni)
    bpp[ni] = Bp + ((size_t)((bn >> 5) + (wn >> 5) + ni) * nktTot + kt0) * 2048 + lane * 8;

  f16f acc[2][2] = {};
  const int swz = l7 ^ ((rsub & 3) << 1);     // row-dependent part of read swizzle
  const int nkt = kLen >> 6;
  for (int kt = 0; kt < nkt; ++kt) {
    // B fragments: coalesced global -> VGPR (1KB per instr)
    h8 breg[2][4];
#pragma unroll
    for (int ni = 0; ni < 2; ++ni)
#pragma unroll
      for (int ks = 0; ks < 4; ++ks)
        breg[ni][ks] = *(const h8*)(bpp[ni] + ks * 512);
    // A tile: global -> LDS DMA
#pragma unroll
    for (int i = 0; i < 4; ++i) {
      gld16(ap[i], al[i]);
      ap[i] += 64;
    }
#pragma unroll
    for (int ni = 0; ni < 2; ++ni) bpp[ni] += 2048;
    __syncthreads();   // drains vmcnt(0): A-DMA (and B loads) complete
    const h8* A8 = (const h8*)As;
#pragma unroll
    for (int ks = 0; ks < 4; ++ks) {
      const int o = (ks * 2 + half) ^ swz;  // swizzled 16B-chunk index
      h8 af[2];
#pragma unroll
      for (int mi = 0; mi < 2; ++mi) af[mi] = A8[(wm + mi * 32 + l31) * 8 + o];
#pragma unroll
      for (int mi = 0; mi < 2; ++mi)
#pragma unroll
        for (int ni = 0; ni < 2; ++ni)
          acc[mi][ni] = __builtin_amdgcn_mfma_f32_32x32x16_f16(af[mi], breg[ni][ks], acc[mi][ni], 0, 0, 0);
    }
    __syncthreads();
  }
  // epilogue: 32x32 C/D layout col=lane&31, row=(reg&3)+8*(reg>>2)+4*(lane>>5)
#pragma unroll
  for (int ni = 0; ni < 2; ++ni) {
    const int col = bn + wn + ni * 32 + l31;
    const float bv = F16OUT ? bias[col] : 0.0f;
#pragma unroll
    for (int mi = 0; mi < 2; ++mi) {
      const int rb = bm + wm + mi * 32 + 4 * half;
#pragma unroll
      for (int reg = 0; reg < 16; ++reg) {
        const int r = rb + (reg & 3) + 8 * (reg >> 2);
        const float v = acc[mi][ni][reg] + bv;
        if (F16OUT)
          ((_Float16*)Cout)[(size_t)r * N + col] = (_Float16)v;
        else
          ((float*)Cout + slice * sliceStride)[(size_t)r * N + col] = v;
      }
    }
  }
}

// ---------- split-K reduce: out = P0 + P1 + bias  (fp32, [8192][768])
__global__ __launch_bounds__(256)
void ksum2(const float* __restrict__ P, const float* __restrict__ bias,
           float* __restrict__ out) {
  const size_t off = ((size_t)blockIdx.x * 256 + threadIdx.x) * 4;
  const int col = (int)(off % 768);
  f4 a = *(const f4*)(P + off);
  f4 b = *(const f4*)(P + (size_t)8192 * 768 + off);
  f4 c = *(const f4*)(bias + col);
  *(f4*)(out + off) = a + b + c;
}

// ---------- flash attention: grid (8 q-tiles, 96 bh). Q-tile 128, KV-tile 64.
__global__ __launch_bounds__(256)
void attn(const _Float16* __restrict__ qkv, const _Float16* __restrict__ Vt,
          float* __restrict__ ctx) {
  __shared__ __align__(16) _Float16 Qs[128 * 64];
  __shared__ __align__(16) _Float16 Ks[64 * 64];
  __shared__ __align__(16) _Float16 Vs[64 * 64];
  __shared__ __align__(16) _Float16 Ps[4 * 32 * 72];
  const int tid = threadIdx.x;
  const int lane = tid & 63, wave = tid >> 6;
  const int bh = blockIdx.y, hh = bh % 12, b = bh / 12;
  const int qt = blockIdx.x;
  const int rsub = lane >> 3;
  const int ksw = ((lane & 7) ^ rsub) * 8;
#pragma unroll
  for (int i = 0; i < 4; ++i) {
    const int ch = wave * 4 + i;
    const int row = ch * 8 + rsub;
    gld16(qkv + (size_t)(b * 1024 + qt * 128 + row) * 2304 + hh * 64 + ksw, Qs + ch * 512);
  }
  const int l16 = lane & 15, quad = lane >> 4, r7 = l16 & 7;
  f4 acc_o[2][4] = {};
  float m_old[2][4], l_sum[2][4];
#pragma unroll
  for (int mi = 0; mi < 2; ++mi)
#pragma unroll
    for (int j = 0; j < 4; ++j) { m_old[mi][j] = -1e30f; l_sum[mi][j] = 0.0f; }

  _Float16* Pw = Ps + wave * (32 * 72);

  for (int kv0 = 0; kv0 < 1024; kv0 += 64) {
#pragma unroll
    for (int i = 0; i < 2; ++i) {
      const int ch = wave * 2 + i;
      const int row = ch * 8 + rsub;
      gld16(qkv + (size_t)(b * 1024 + kv0 + row) * 2304 + 768 + hh * 64 + ksw, Ks + ch * 512);
      gld16(Vt + (size_t)(bh * 64 + row) * 1024 + kv0 + ksw, Vs + ch * 512);
    }
    __syncthreads();
    const h8* Q8 = (const h8*)Qs;
    const h8* K8 = (const h8*)Ks;
    const h8* V8 = (const h8*)Vs;
    f4 s[2][4] = {};
#pragma unroll
    for (int ks = 0; ks < 2; ++ks) {
      const int kq = (ks * 4 + quad) ^ r7;
      h8 qf[2], kf[4];
#pragma unroll
      for (int mi = 0; mi < 2; ++mi) qf[mi] = Q8[(wave * 32 + mi * 16 + l16) * 8 + kq];
#pragma unroll
      for (int ni = 0; ni < 4; ++ni) kf[ni] = K8[(ni * 16 + l16) * 8 + kq];
#pragma unroll
      for (int mi = 0; mi < 2; ++mi)
#pragma unroll
        for (int ni = 0; ni < 4; ++ni)
          s[mi][ni] = __builtin_amdgcn_mfma_f32_16x16x32_f16(qf[mi], kf[ni], s[mi][ni], 0, 0, 0);
    }
#pragma unroll
    for (int mi = 0; mi < 2; ++mi)
#pragma unroll
      for (int ni = 0; ni < 4; ++ni) s[mi][ni] *= 0.125f;  // d^-0.5, d=64
#pragma unroll
    for (int mi = 0; mi < 2; ++mi) {
#pragma unroll
      for (int j = 0; j < 4; ++j) {
        float vm = fmaxf(fmaxf(s[mi][0][j], s[mi][1][j]), fmaxf(s[mi][2][j], s[mi][3][j]));
#pragma unroll
        for (int off = 1; off < 16; off <<= 1) vm = fmaxf(vm, __shfl_xor(vm, off));
        const float mn = fmaxf(m_old[mi][j], vm);
        const float alpha = __expf(m_old[mi][j] - mn);
        float rs = 0.0f;
#pragma unroll
        for (int ni = 0; ni < 4; ++ni) {
          const float p = __expf(s[mi][ni][j] - mn);
          s[mi][ni][j] = p;
          rs += p;
        }
#pragma unroll
        for (int off = 1; off < 16; off <<= 1) rs += __shfl_xor(rs, off);
        l_sum[mi][j] = l_sum[mi][j] * alpha + rs;
        m_old[mi][j] = mn;
#pragma unroll
        for (int ni = 0; ni < 4; ++ni) acc_o[mi][ni][j] *= alpha;
      }
    }
#pragma unroll
    for (int mi = 0; mi < 2; ++mi)
#pragma unroll
      for (int ni = 0; ni < 4; ++ni)
#pragma unroll
        for (int j = 0; j < 4; ++j)
          Pw[(mi * 16 + quad * 4 + j) * 72 + ni * 16 + l16] = (_Float16)s[mi][ni][j];
#pragma unroll
    for (int ks = 0; ks < 2; ++ks) {
      const int kq = ks * 4 + quad;
      h8 pf[2], vf[4];
#pragma unroll
      for (int mi = 0; mi < 2; ++mi) pf[mi] = *(const h8*)(Pw + (mi * 16 + l16) * 72 + kq * 8);
#pragma unroll
      for (int ni = 0; ni < 4; ++ni) vf[ni] = V8[(ni * 16 + l16) * 8 + (kq ^ r7)];
#pragma unroll
      for (int mi = 0; mi < 2; ++mi)
#pragma unroll
        for (int ni = 0; ni < 4; ++ni)
          acc_o[mi][ni] = __builtin_amdgcn_mfma_f32_16x16x32_f16(pf[mi], vf[ni], acc_o[mi][ni], 0, 0, 0);
    }
    __syncthreads();
  }
#pragma unroll
  for (int mi = 0; mi < 2; ++mi) {
#pragma unroll
    for (int j = 0; j < 4; ++j) {
      const float inv = 1.0f / l_sum[mi][j];
      const int tok = b * 1024 + qt * 128 + wave * 32 + mi * 16 + quad * 4 + j;
      float* cr = ctx + (size_t)tok * 768 + hh * 64;
#pragma unroll
      for (int ni = 0; ni < 4; ++ni) cr[ni * 16 + l16] = acc_o[mi][ni][j] * inv;
    }
  }
}

extern "C" void kernel_launch(void* const* d_in, const int* in_sizes, int n_in,
                              void* d_out, int out_size, void* d_ws, size_t ws_size,
                              hipStream_t stream) {
  (void)in_sizes; (void)n_in; (void)out_size; (void)ws_size;
  const float* x    = (const float*)d_in[0];
  const float* qlnw = (const float*)d_in[1];
  const float* qlnb = (const float*)d_in[2];
  const float* qsw  = (const float*)d_in[3];
  const float* qbw  = (const float*)d_in[4];
  const float* qbb  = (const float*)d_in[5];
  const float* plnw = (const float*)d_in[6];
  const float* plnb = (const float*)d_in[7];
  const float* psw  = (const float*)d_in[8];
  const float* pbw  = (const float*)d_in[9];
  const float* pbb  = (const float*)d_in[10];
  float* out = (float*)d_out;

  // workspace layout (fp16 unless noted), ~231 MB total
  _Float16* WtQ  = (_Float16*)d_ws;                  // [2304][6912] fragment-order
  _Float16* WtP  = WtQ + (size_t)2304 * 6912;        // [768][6912] fragment-order
  _Float16* Acat = WtP + (size_t)768 * 6912;         // [8192][6912] (reused)
  _Float16* QKV  = Acat + (size_t)8192 * 6912;       // [8192][2304]
  _Float16* Vt   = QKV + (size_t)8192 * 2304;        // [96*64][1024]
  float* CTX = (float*)(Vt + (size_t)96 * 64 * 1024);  // [8192][768] fp32
  // split-K partials alias the dead QKV+Vt region (exactly 2*8192*768*4 B)
  float* Pp = (float*)QKV;

  dim3 blk(256);
  // weights -> fp16, fragment-swizzled (K total 6912 -> nkt=108)
  wt_cast<<<dim3(192, 72), blk, 0, stream>>>(qsw, WtQ, 2304, 0, 108);
  wt_cast<<<dim3(24, 72),  blk, 0, stream>>>(qbw, WtQ, 2304, 6144, 108);
  wt_cast<<<dim3(192, 24), blk, 0, stream>>>(psw, WtP, 768, 0, 108);
  wt_cast<<<dim3(24, 24),  blk, 0, stream>>>(pbw, WtP, 768, 6144, 108);
  // FastKAN 1 -> qkv
  kan_prep<<<8192, blk, 0, stream>>>(x, qlnw, qlnb, Acat);
  gemm_bt<true><<<dim3(2304 / 128, 8192 / 128, 1), blk, 0, stream>>>(
      Acat, WtQ, qbb, QKV, 2304, 6912, 6912, 0);
  // attention
  v_transpose<<<dim3(32, 2, 96), blk, 0, stream>>>(QKV, Vt);
  attn<<<dim3(8, 96), blk, 0, stream>>>(QKV, Vt, CTX);
  // FastKAN 2 -> out (split-K=2 over dead QKV/Vt memory, then reduce+bias)
  kan_prep<<<8192, blk, 0, stream>>>(CTX, plnw, plnb, Acat);
  gemm_bt<false><<<dim3(768 / 128, 8192 / 128, 2), blk, 0, stream>>>(
      Acat, WtP, nullptr, Pp, 768, 6912, 3456, (size_t)8192 * 768);
  ksum2<<<8192 * 768 / 4 / 256, blk, 0, stream>>>(Pp, pbb, out);
}

// Round 7
// 698.769 us; speedup vs baseline: 1.5826x; 1.0914x over previous
//
#include <hip/hip_runtime.h>
#include <cstdint>
#include <cstddef>

typedef _Float16 h8 __attribute__((ext_vector_type(8)));
typedef float f4 __attribute__((ext_vector_type(4)));
typedef float f16f __attribute__((ext_vector_type(16)));

#define DEV static __device__ __forceinline__

DEV void gld16(const void* g, void* l) {
  __builtin_amdgcn_global_load_lds(
      (const __attribute__((address_space(1))) void*)g,
      (__attribute__((address_space(3))) void*)l, 16, 0, 0);
}

// ---------- FastKAN prep: LayerNorm + RBF basis + SiLU -> Acat [M][6912] fp16
__global__ __launch_bounds__(256)
void kan_prep(const float* __restrict__ X, const float* __restrict__ lnw,
              const float* __restrict__ lnb, _Float16* __restrict__ Acat) {
  const int row = blockIdx.x;
  const int tid = threadIdx.x;
  const float* xr = X + (size_t)row * 768;
  float xv[3];
  xv[0] = xr[tid]; xv[1] = xr[tid + 256]; xv[2] = xr[tid + 512];
  float s = xv[0] + xv[1] + xv[2];
  float q = xv[0] * xv[0] + xv[1] * xv[1] + xv[2] * xv[2];
#pragma unroll
  for (int off = 32; off; off >>= 1) {
    s += __shfl_xor(s, off);
    q += __shfl_xor(q, off);
  }
  __shared__ float rs_[4], rq_[4];
  const int wave = tid >> 6;
  if ((tid & 63) == 0) { rs_[wave] = s; rq_[wave] = q; }
  __syncthreads();
  s = rs_[0] + rs_[1] + rs_[2] + rs_[3];
  q = rq_[0] + rq_[1] + rq_[2] + rq_[3];
  const float mu = s * (1.0f / 768.0f);
  const float var = q * (1.0f / 768.0f) - mu * mu;
  const float rsig = rsqrtf(var + 1e-5f);
  _Float16* out = Acat + (size_t)row * 6912;
#pragma unroll
  for (int i = 0; i < 3; ++i) {
    const int c = tid + i * 256;
    const float x = xv[i];
    const float h = (x - mu) * rsig * lnw[c] + lnb[c];
    union { h8 v; _Float16 u[8]; } bs;
#pragma unroll
    for (int g = 0; g < 8; ++g) {
      const float gv = -2.0f + (4.0f / 7.0f) * (float)g;
      const float t = (h - gv) * 1.75f;  // 1/DENOM = 7/4
      bs.u[g] = (_Float16)__expf(-t * t);
    }
    *(h8*)(out + c * 8) = bs.v;
    out[6144 + c] = (_Float16)(x / (1.0f + __expf(-x)));  // silu
  }
}

// ---------- weight cast + FRAGMENT-SWIZZLE: W fp32 [K][N] -> Bp fp16 in exact
// MFMA B-fragment order: 16B frag (n, k..k+7) at elem addr
//   ((n>>5)*nkt + (k>>6))*2048 + (((k>>4)&3)*64 + (n&31) + 32*((k>>3)&1))*8
__global__ __launch_bounds__(256)
void wt_cast(const float* __restrict__ W, _Float16* __restrict__ Bp,
             int N, int koff, int nkt) {
  __shared__ float t[32][33];
  const int k0 = blockIdx.x * 32, n0 = blockIdx.y * 32;
  const int tx = threadIdx.x & 31, ty = threadIdx.x >> 5;
#pragma unroll
  for (int i = 0; i < 4; ++i)
    t[ty + i * 8][tx] = W[(size_t)(k0 + ty + i * 8) * N + n0 + tx];
  __syncthreads();
  const int f = threadIdx.x;
  if (f < 128) {
    const int nn = f & 31, cc = f >> 5;          // cc: which 8-elem k-chunk
    union { h8 v; _Float16 u[8]; } bs;
#pragma unroll
    for (int j = 0; j < 8; ++j) bs.u[j] = (_Float16)t[cc * 8 + j][nn];
    const int kg = koff + k0 + cc * 8;           // global k of chunk start
    const int nt = (n0 + nn) >> 5;
    const size_t addr = ((size_t)nt * nkt + (kg >> 6)) * 2048 +
                        (size_t)((((kg >> 4) & 3) * 64 + nn + 32 * ((kg >> 3) & 1))) * 8;
    *(h8*)(Bp + addr) = bs.v;
  }
}

// ---------- V transpose: qkv fp16 [8192][2304] -> Vt [96*64][1024]
__global__ __launch_bounds__(256)
void v_transpose(const _Float16* __restrict__ qkv, _Float16* __restrict__ Vt) {
  const int bh = blockIdx.z, hh = bh % 12, b = bh / 12;
  const int kvb = blockIdx.x * 32, db = blockIdx.y * 32;
  __shared__ _Float16 t[32][33];
  const int tx = threadIdx.x & 31, ty = threadIdx.x >> 5;
#pragma unroll
  for (int i = 0; i < 4; ++i) {
    const int kv = kvb + ty + i * 8;
    t[ty + i * 8][tx] = qkv[(size_t)(b * 1024 + kv) * 2304 + 1536 + hh * 64 + db + tx];
  }
  __syncthreads();
#pragma unroll
  for (int i = 0; i < 4; ++i) {
    const int d = db + ty + i * 8;
    Vt[(size_t)(bh * 64 + d) * 1024 + kvb + tx] = t[tx][ty + i * 8];
  }
}

// ---------- fp16 GEMM, r7: PIPELINED K-loop. A double-buffered in LDS (2x16KB,
// global_load_lds DMA); B in VGPRs from fragment-order global, double-buffered.
// One barrier per BK=64 iter; next iter's loads issue RIGHT AFTER the barrier,
// so the mandatory vmcnt(0) drain at the following barrier is pre-covered by
// ~512 cyc of MFMA (r6 measured 1718 cyc/block-iter vs 516 MFMA demand — the
// gap was the un-overlapped drain). XCD swizzle: lin%8 picks XCD, contiguous
// 8-M-row band per XCD for A-panel L2 locality (r6 FETCH 950MB vs 145 unique).
#define LOAD_B(dst)                                       \
  {                                                       \
    _Pragma("unroll") for (int ni = 0; ni < 2; ++ni) {    \
      _Pragma("unroll") for (int ks = 0; ks < 4; ++ks)    \
        dst[ni][ks] = *(const h8*)(bpp[ni] + ks * 512);   \
      bpp[ni] += 2048;                                    \
    }                                                     \
  }
#define LOAD_A(buf)                                       \
  {                                                       \
    _Pragma("unroll") for (int i = 0; i < 4; ++i) {       \
      gld16(ap[i], (buf) + alOff[i]);                     \
      ap[i] += 64;                                        \
    }                                                     \
  }
#define MFMA_STEP(buf, br)                                \
  {                                                       \
    const h8* A8 = (const h8*)(buf);                      \
    _Pragma("unroll") for (int ks = 0; ks < 4; ++ks) {    \
      const int o = (ks * 2 + half) ^ swz;                \
      h8 af0 = A8[(wm + l31) * 8 + o];                    \
      h8 af1 = A8[(wm + 32 + l31) * 8 + o];               \
      acc[0][0] = __builtin_amdgcn_mfma_f32_32x32x16_f16(af0, br[0][ks], acc[0][0], 0, 0, 0); \
      acc[0][1] = __builtin_amdgcn_mfma_f32_32x32x16_f16(af0, br[1][ks], acc[0][1], 0, 0, 0); \
      acc[1][0] = __builtin_amdgcn_mfma_f32_32x32x16_f16(af1, br[0][ks], acc[1][0], 0, 0, 0); \
      acc[1][1] = __builtin_amdgcn_mfma_f32_32x32x16_f16(af1, br[1][ks], acc[1][1], 0, 0, 0); \
    }                                                     \
  }

template <bool F16OUT>
__global__ __launch_bounds__(256, 2)
void gemm_bt(const _Float16* __restrict__ A, const _Float16* __restrict__ Bp,
             const float* __restrict__ bias, void* __restrict__ Cout,
             int N, int ldK, int kLen, size_t sliceStride) {
  __shared__ __align__(16) _Float16 As[2 * 128 * 64];
  _Float16* As0 = As;
  _Float16* As1 = As + 128 * 64;
  const int tid = threadIdx.x;
  const int lane = tid & 63, wave = tid >> 6;
  // XCD-aware block swizzle: lin%8 = XCD (round-robin dispatch heuristic);
  // each XCD covers a contiguous band of gridDim.y/8 M-blocks.
  const int gx = gridDim.x;
  const int lin = blockIdx.y * gx + blockIdx.x;
  const int xcd = lin & 7, pos = lin >> 3;
  const int bandH = gridDim.y >> 3;
  const int bm = (xcd * bandH + pos / gx) * 128;
  const int bn = (pos % gx) * 128;
  const int slice = blockIdx.z;
  const int kOff = slice * kLen;
  const int rsub = lane >> 3;                 // row within 8-row staging chunk
  const int l7 = lane & 7;
  const int l31 = lane & 31, half = lane >> 5;
  const int wm = (wave >> 1) * 64, wn = (wave & 1) * 64;
  const _Float16* ap[4];
  int alOff[4];
#pragma unroll
  for (int i = 0; i < 4; ++i) {
    const int ch = wave * 4 + i;
    // swizzled store: chunk c of row r -> slot r*8 + (c ^ (r&7) ^ ((r>>3&3)<<1))
    const int ksw = (l7 ^ rsub ^ ((ch & 3) << 1)) * 8;
    ap[i] = A + (size_t)(bm + ch * 8 + rsub) * ldK + kOff + ksw;
    alOff[i] = ch * 512;
  }
  const size_t nktTot = (size_t)(ldK >> 6);
  const int kt0 = kOff >> 6;
  const _Float16* bpp[2];
#pragma unroll
  for (int ni = 0; ni < 2; ++ni)
    bpp[ni] = Bp + ((size_t)((bn >> 5) + (wn >> 5) + ni) * nktTot + kt0) * 2048 + lane * 8;

  f16f acc[2][2] = {};
  const int swz = l7 ^ ((rsub & 3) << 1);     // row-dependent part of read swizzle
  const int nkt = kLen >> 6;                  // even (108 or 54)
  h8 bregA[2][4], bregB[2][4];
  LOAD_B(bregA);
  LOAD_A(As0);
  for (int kt = 0; kt < nkt; kt += 2) {
    __syncthreads();                          // drains A(kt) DMA (+B), pre-covered
    if (kt + 1 < nkt) { LOAD_B(bregB); LOAD_A(As1); }
    MFMA_STEP(As0, bregA);
    __syncthreads();
    if (kt + 2 < nkt) { LOAD_B(bregA); LOAD_A(As0); }
    MFMA_STEP(As1, bregB);
  }
  // epilogue: 32x32 C/D layout col=lane&31, row=(reg&3)+8*(reg>>2)+4*(lane>>5)
#pragma unroll
  for (int ni = 0; ni < 2; ++ni) {
    const int col = bn + wn + ni * 32 + l31;
    const float bv = F16OUT ? bias[col] : 0.0f;
#pragma unroll
    for (int mi = 0; mi < 2; ++mi) {
      const int rb = bm + wm + mi * 32 + 4 * half;
#pragma unroll
      for (int reg = 0; reg < 16; ++reg) {
        const int r = rb + (reg & 3) + 8 * (reg >> 2);
        const float v = acc[mi][ni][reg] + bv;
        if (F16OUT)
          ((_Float16*)Cout)[(size_t)r * N + col] = (_Float16)v;
        else
          ((float*)Cout + slice * sliceStride)[(size_t)r * N + col] = v;
      }
    }
  }
}

// ---------- split-K reduce: out = P0 + P1 + bias  (fp32, [8192][768])
__global__ __launch_bounds__(256)
void ksum2(const float* __restrict__ P, const float* __restrict__ bias,
           float* __restrict__ out) {
  const size_t off = ((size_t)blockIdx.x * 256 + threadIdx.x) * 4;
  const int col = (int)(off % 768);
  f4 a = *(const f4*)(P + off);
  f4 b = *(const f4*)(P + (size_t)8192 * 768 + off);
  f4 c = *(const f4*)(bias + col);
  *(f4*)(out + off) = a + b + c;
}

// ---------- flash attention: grid (8 q-tiles, 96 bh). Q-tile 128, KV-tile 64.
__global__ __launch_bounds__(256)
void attn(const _Float16* __restrict__ qkv, const _Float16* __restrict__ Vt,
          float* __restrict__ ctx) {
  __shared__ __align__(16) _Float16 Qs[128 * 64];
  __shared__ __align__(16) _Float16 Ks[64 * 64];
  __shared__ __align__(16) _Float16 Vs[64 * 64];
  __shared__ __align__(16) _Float16 Ps[4 * 32 * 72];
  const int tid = threadIdx.x;
  const int lane = tid & 63, wave = tid >> 6;
  const int bh = blockIdx.y, hh = bh % 12, b = bh / 12;
  const int qt = blockIdx.x;
  const int rsub = lane >> 3;
  const int ksw = ((lane & 7) ^ rsub) * 8;
#pragma unroll
  for (int i = 0; i < 4; ++i) {
    const int ch = wave * 4 + i;
    const int row = ch * 8 + rsub;
    gld16(qkv + (size_t)(b * 1024 + qt * 128 + row) * 2304 + hh * 64 + ksw, Qs + ch * 512);
  }
  const int l16 = lane & 15, quad = lane >> 4, r7 = l16 & 7;
  f4 acc_o[2][4] = {};
  float m_old[2][4], l_sum[2][4];
#pragma unroll
  for (int mi = 0; mi < 2; ++mi)
#pragma unroll
    for (int j = 0; j < 4; ++j) { m_old[mi][j] = -1e30f; l_sum[mi][j] = 0.0f; }

  _Float16* Pw = Ps + wave * (32 * 72);

  for (int kv0 = 0; kv0 < 1024; kv0 += 64) {
#pragma unroll
    for (int i = 0; i < 2; ++i) {
      const int ch = wave * 2 + i;
      const int row = ch * 8 + rsub;
      gld16(qkv + (size_t)(b * 1024 + kv0 + row) * 2304 + 768 + hh * 64 + ksw, Ks + ch * 512);
      gld16(Vt + (size_t)(bh * 64 + row) * 1024 + kv0 + ksw, Vs + ch * 512);
    }
    __syncthreads();
    const h8* Q8 = (const h8*)Qs;
    const h8* K8 = (const h8*)Ks;
    const h8* V8 = (const h8*)Vs;
    f4 s[2][4] = {};
#pragma unroll
    for (int ks = 0; ks < 2; ++ks) {
      const int kq = (ks * 4 + quad) ^ r7;
      h8 qf[2], kf[4];
#pragma unroll
      for (int mi = 0; mi < 2; ++mi) qf[mi] = Q8[(wave * 32 + mi * 16 + l16) * 8 + kq];
#pragma unroll
      for (int ni = 0; ni < 4; ++ni) kf[ni] = K8[(ni * 16 + l16) * 8 + kq];
#pragma unroll
      for (int mi = 0; mi < 2; ++mi)
#pragma unroll
        for (int ni = 0; ni < 4; ++ni)
          s[mi][ni] = __builtin_amdgcn_mfma_f32_16x16x32_f16(qf[mi], kf[ni], s[mi][ni], 0, 0, 0);
    }
#pragma unroll
    for (int mi = 0; mi < 2; ++mi)
#pragma unroll
      for (int ni = 0; ni < 4; ++ni) s[mi][ni] *= 0.125f;  // d^-0.5, d=64
#pragma unroll
    for (int mi = 0; mi < 2; ++mi) {
#pragma unroll
      for (int j = 0; j < 4; ++j) {
        float vm = fmaxf(fmaxf(s[mi][0][j], s[mi][1][j]), fmaxf(s[mi][2][j], s[mi][3][j]));
#pragma unroll
        for (int off = 1; off < 16; off <<= 1) vm = fmaxf(vm, __shfl_xor(vm, off));
        const float mn = fmaxf(m_old[mi][j], vm);
        const float alpha = __expf(m_old[mi][j] - mn);
        float rs = 0.0f;
#pragma unroll
        for (int ni = 0; ni < 4; ++ni) {
          const float p = __expf(s[mi][ni][j] - mn);
          s[mi][ni][j] = p;
          rs += p;
        }
#pragma unroll
        for (int off = 1; off < 16; off <<= 1) rs += __shfl_xor(rs, off);
        l_sum[mi][j] = l_sum[mi][j] * alpha + rs;
        m_old[mi][j] = mn;
#pragma unroll
        for (int ni = 0; ni < 4; ++ni) acc_o[mi][ni][j] *= alpha;
      }
    }
#pragma unroll
    for (int mi = 0; mi < 2; ++mi)
#pragma unroll
      for (int ni = 0; ni < 4; ++ni)
#pragma unroll
        for (int j = 0; j < 4; ++j)
          Pw[(mi * 16 + quad * 4 + j) * 72 + ni * 16 + l16] = (_Float16)s[mi][ni][j];
#pragma unroll
    for (int ks = 0; ks < 2; ++ks) {
      const int kq = ks * 4 + quad;
      h8 pf[2], vf[4];
#pragma unroll
      for (int mi = 0; mi < 2; ++mi) pf[mi] = *(const h8*)(Pw + (mi * 16 + l16) * 72 + kq * 8);
#pragma unroll
      for (int ni = 0; ni < 4; ++ni) vf[ni] = V8[(ni * 16 + l16) * 8 + (kq ^ r7)];
#pragma unroll
      for (int mi = 0; mi < 2; ++mi)
#pragma unroll
        for (int ni = 0; ni < 4; ++ni)
          acc_o[mi][ni] = __builtin_amdgcn_mfma_f32_16x16x32_f16(pf[mi], vf[ni], acc_o[mi][ni], 0, 0, 0);
    }
    __syncthreads();
  }
#pragma unroll
  for (int mi = 0; mi < 2; ++mi) {
#pragma unroll
    for (int j = 0; j < 4; ++j) {
      const float inv = 1.0f / l_sum[mi][j];
      const int tok = b * 1024 + qt * 128 + wave * 32 + mi * 16 + quad * 4 + j;
      float* cr = ctx + (size_t)tok * 768 + hh * 64;
#pragma unroll
      for (int ni = 0; ni < 4; ++ni) cr[ni * 16 + l16] = acc_o[mi][ni][j] * inv;
    }
  }
}

extern "C" void kernel_launch(void* const* d_in, const int* in_sizes, int n_in,
                              void* d_out, int out_size, void* d_ws, size_t ws_size,
                              hipStream_t stream) {
  (void)in_sizes; (void)n_in; (void)out_size; (void)ws_size;
  const float* x    = (const float*)d_in[0];
  const float* qlnw = (const float*)d_in[1];
  const float* qlnb = (const float*)d_in[2];
  const float* qsw  = (const float*)d_in[3];
  const float* qbw  = (const float*)d_in[4];
  const float* qbb  = (const float*)d_in[5];
  const float* plnw = (const float*)d_in[6];
  const float* plnb = (const float*)d_in[7];
  const float* psw  = (const float*)d_in[8];
  const float* pbw  = (const float*)d_in[9];
  const float* pbb  = (const float*)d_in[10];
  float* out = (float*)d_out;

  // workspace layout (fp16 unless noted), ~231 MB total
  _Float16* WtQ  = (_Float16*)d_ws;                  // [2304][6912] fragment-order
  _Float16* WtP  = WtQ + (size_t)2304 * 6912;        // [768][6912] fragment-order
  _Float16* Acat = WtP + (size_t)768 * 6912;         // [8192][6912] (reused)
  _Float16* QKV  = Acat + (size_t)8192 * 6912;       // [8192][2304]
  _Float16* Vt   = QKV + (size_t)8192 * 2304;        // [96*64][1024]
  float* CTX = (float*)(Vt + (size_t)96 * 64 * 1024);  // [8192][768] fp32
  // split-K partials alias the dead QKV+Vt region (exactly 2*8192*768*4 B)
  float* Pp = (float*)QKV;

  dim3 blk(256);
  // weights -> fp16, fragment-swizzled (K total 6912 -> nkt=108)
  wt_cast<<<dim3(192, 72), blk, 0, stream>>>(qsw, WtQ, 2304, 0, 108);
  wt_cast<<<dim3(24, 72),  blk, 0, stream>>>(qbw, WtQ, 2304, 6144, 108);
  wt_cast<<<dim3(192, 24), blk, 0, stream>>>(psw, WtP, 768, 0, 108);
  wt_cast<<<dim3(24, 24),  blk, 0, stream>>>(pbw, WtP, 768, 6144, 108);
  // FastKAN 1 -> qkv
  kan_prep<<<8192, blk, 0, stream>>>(x, qlnw, qlnb, Acat);
  gemm_bt<true><<<dim3(2304 / 128, 8192 / 128, 1), blk, 0, stream>>>(
      Acat, WtQ, qbb, QKV, 2304, 6912, 6912, 0);
  // attention
  v_transpose<<<dim3(32, 2, 96), blk, 0, stream>>>(QKV, Vt);
  attn<<<dim3(8, 96), blk, 0, stream>>>(QKV, Vt, CTX);
  // FastKAN 2 -> out (split-K=2 over dead QKV/Vt memory, then reduce+bias)
  kan_prep<<<8192, blk, 0, stream>>>(CTX, plnw, plnb, Acat);
  gemm_bt<false><<<dim3(768 / 128, 8192 / 128, 2), blk, 0, stream>>>(
      Acat, WtP, nullptr, Pp, 768, 6912, 3456, (size_t)8192 * 768);
  ksum2<<<8192 * 768 / 4 / 256, blk, 0, stream>>>(Pp, pbb, out);
}